// Round 9
// baseline (176.548 us; speedup 1.0000x reference)
//
#include <hip/hip_runtime.h>
#include <hip/hip_bf16.h>
#include <stdint.h>

typedef unsigned short u16;
typedef unsigned char u8;
typedef unsigned long long u64;
typedef __attribute__((ext_vector_type(8))) short short8;
typedef __attribute__((ext_vector_type(4))) float float4v;
typedef __attribute__((ext_vector_type(2))) _Float16 v2h;

// RNE float->bf16
__device__ __forceinline__ u16 f2bf(float x) {
    union { float f; unsigned int u; } v; v.f = x;
    unsigned int r = v.u + 0x7fffu + ((v.u >> 16) & 1u);
    return (u16)(r >> 16);
}

// bitcast u32 -> packed f16 pair
__device__ __forceinline__ v2h mk2h(unsigned int u) {
    union { unsigned int u; v2h h; } c; c.u = u; return c.h;
}

// packed fp16 dot-accumulate: s += a.x*b.x + a.y*b.y (fp32 acc)
__device__ __forceinline__ float dot2acc(v2h a, v2h b, float s) {
#if __has_builtin(__builtin_amdgcn_fdot2)
    return __builtin_amdgcn_fdot2(a, b, s, false);
#else
    return fmaf((float)a[0], (float)b[0], fmaf((float)a[1], (float)b[1], s));
#endif
}

// byte-pair -> f16-pair [b, 0x64] via v_perm_b32 (1 op); fallback = and_or path.
__device__ __forceinline__ unsigned perm_even(unsigned x, unsigned k64) {
#if __has_builtin(__builtin_amdgcn_perm)
    return __builtin_amdgcn_perm(x, k64, 0x00060004u);
#else
    return (x & 0x00FF00FFu) | 0x64006400u;
#endif
}
__device__ __forceinline__ unsigned perm_odd(unsigned x, unsigned k64) {
#if __has_builtin(__builtin_amdgcn_perm)
    return __builtin_amdgcn_perm(x, k64, 0x00070005u);
#else
    return ((x >> 8) & 0x00FF00FFu) | 0x64006400u;
#endif
}

// ============================================================================
// int8 U/V storage: PERMUTED per-row layout, PRE-BIASED unsigned:
//   byte p of a row holds (q_col(p) + 128), col(p) = (p&7)*16 + (p>>3)
// ============================================================================

// ---------------- Pass 0: pack W1 into B-frag layout + zero bin cursors ----------
__global__ __launch_bounds__(256) void w1_pack(
    const float* __restrict__ W1, u16* __restrict__ w1p, int* __restrict__ cursor)
{
    if (blockIdx.x == 0 && threadIdx.x < 8) cursor[threadIdx.x] = 0;
    int w = blockIdx.x * 256 + threadIdx.x;   // 0..4095
    int lanep = w & 63, t = (w >> 6) & 7, kc = w >> 9;
    short8 o;
#pragma unroll
    for (int j = 0; j < 8; ++j) {
        int k = kc * 32 + (lanep >> 4) * 8 + j;
        int n = t * 16 + (lanep & 15);
        o[j] = (short)f2bf(W1[k * 128 + n]);
    }
    *(short8*)(w1p + (size_t)w * 8) = o;
}

// ---------------- Pass 1 (merged): dense GEMMs + edge binning --------------------
// ROUND-9 RESTRUCTURE of the GEMM role. Round-8 counters: VGPR 68 + 64 AGPR acc
// = 132 regs -> 3 waves/SIMD AND no spare VGPRs for the 16-deep A-load batch ->
// compiler serialized loads -> latency chain (41us, Occ 23%, 1.7TB/s, MfmaUtil
// 4%). Fix: 64-row tiles (wave owns 16 rows): acc 32 AGPR, A-batch 8 loads =
// 32 VGPR all in flight, launch_bounds(256,4) -> 4 waves/SIMD. ~3-5x in-flight
// bytes/CU. B-frag L2 duplication doubles (300MB ~ 9us at 34TB/s, overlapped).
__global__ __launch_bounds__(256, 4) void gemm_bin(
    const float* __restrict__ zs, const float* __restrict__ zt,
    const u16* __restrict__ w1p, const float* __restrict__ b1,
    u8* __restrict__ U8, u8* __restrict__ V8,
    float* __restrict__ su, float* __restrict__ sv,
    int M1, int M2, int nU, int nGemm,
    const int* __restrict__ row, const int* __restrict__ col,
    u64* __restrict__ tup, int* __restrict__ cursor,
    int E, float binv, int C,
    const float* __restrict__ W1, const float* __restrict__ W2,
    const float* __restrict__ b2, float* __restrict__ out)
{
    __shared__ int lcnt[8];
    __shared__ int lbase[8];

    if ((int)blockIdx.x < nGemm) {
        // ---------------- GEMM role: 64-row tile, LDS-free streaming ------------
        const int tid = threadIdx.x, wave = tid >> 6, lane = tid & 63;
        const int m15 = lane & 15, quad = lane >> 4;
        const bool isV = (int)blockIdx.x >= nU;
        const float* zsrc = isV ? zt : zs;
        u8* dst = isV ? V8 : U8;
        float* sdst = isV ? sv : su;
        const int row0 = (isV ? ((int)blockIdx.x - nU) : (int)blockIdx.x) * 64;
        const int M = isV ? M2 : M1;
        const int nrows = (M - row0) < 64 ? (M - row0) : 64;
        const char* wsrc = (const char*)(w1p + (isV ? 16384 : 0));

        // A: 8 dwordx4 loads, ALL in flight (32 VGPR). Wave owns rows
        // [wave*16, +16); lane holds A[wave*16+m15][kc*32 + quad*8 .. +8].
        const int r = wave * 16 + m15;
        const int rcl = r < nrows ? r : (nrows - 1);
        const float* rowp = zsrc + (size_t)(row0 + rcl) * 128 + quad * 8;
        float4 afl[4][2];
#pragma unroll
        for (int kc = 0; kc < 4; ++kc) {
            afl[kc][0] = *(const float4*)(rowp + kc * 32);
            afl[kc][1] = *(const float4*)(rowp + kc * 32 + 4);
        }
        short8 Af[4];
#pragma unroll
        for (int kc = 0; kc < 4; ++kc) {
            float4 x = afl[kc][0], y = afl[kc][1];
            short8 o;
            o[0] = (short)f2bf(x.x); o[1] = (short)f2bf(x.y);
            o[2] = (short)f2bf(x.z); o[3] = (short)f2bf(x.w);
            o[4] = (short)f2bf(y.x); o[5] = (short)f2bf(y.y);
            o[6] = (short)f2bf(y.z); o[7] = (short)f2bf(y.w);
            Af[kc] = o;
        }

        float4v acc[8];
#pragma unroll
        for (int b = 0; b < 8; ++b)
            acc[b] = (float4v){0.f, 0.f, 0.f, 0.f};

#pragma unroll
        for (int kc = 0; kc < 4; ++kc) {
            short8 Bf[8];
#pragma unroll
            for (int t = 0; t < 8; ++t)
                Bf[t] = *(const short8*)(wsrc + ((kc * 8 + t) * 1024 + lane * 16));
#pragma unroll
            for (int t = 0; t < 8; ++t)
                acc[t] = __builtin_amdgcn_mfma_f32_16x16x32_bf16(
                    Af[kc], Bf[t], acc[t], 0, 0, 0);
        }

        // epilogue: +b1 (U only), per-row absmax -> int8, pack, dwordx2 store.
        // C/D frag: col = t*16 + m15, row(in 16-tile) = quad*4 + rr_i.
        float b1v[8];
#pragma unroll
        for (int t = 0; t < 8; ++t) b1v[t] = isV ? 0.f : b1[t * 16 + m15];

#pragma unroll
        for (int ri = 0; ri < 4; ++ri) {
            const int rr = wave * 16 + quad * 4 + ri;
            float vals[8];
            float vmax = 0.f;
#pragma unroll
            for (int t = 0; t < 8; ++t) {
                float x = acc[t][ri] + b1v[t];
                vals[t] = x;
                vmax = fmaxf(vmax, fabsf(x));
            }
            vmax = fmaxf(vmax, __shfl_xor(vmax, 1));
            vmax = fmaxf(vmax, __shfl_xor(vmax, 2));
            vmax = fmaxf(vmax, __shfl_xor(vmax, 4));
            vmax = fmaxf(vmax, __shfl_xor(vmax, 8));
            const float scl = vmax * (1.f / 127.f);
            const float rs = vmax > 0.f ? 127.f / vmax : 0.f;
            if (rr < nrows) {
                if (m15 == 0) sdst[row0 + rr] = scl;
                unsigned wlo = 0, whi = 0;
#pragma unroll
                for (int t = 0; t < 4; ++t) {
                    int q = __float2int_rn(vals[t] * rs);
                    q = q > 127 ? 127 : (q < -127 ? -127 : q);
                    wlo |= (unsigned)(q + 128) << (8 * t);   // pre-biased
                }
#pragma unroll
                for (int t = 4; t < 8; ++t) {
                    int q = __float2int_rn(vals[t] * rs);
                    q = q > 127 ? 127 : (q < -127 ? -127 : q);
                    whi |= (unsigned)(q + 128) << (8 * (t - 4));
                }
                uint2 pk; pk.x = wlo; pk.y = whi;
                *(uint2*)(dst + (size_t)(row0 + rr) * 128 + m15 * 8) = pk;
            }
        }
    } else {
        // ---------------- BIN role (XCD partitioning by U-row octant) ----------
        const int tid = threadIdx.x;
        if (tid < 8) lcnt[tid] = 0;
        __syncthreads();
        const int eb = ((int)blockIdx.x - nGemm) * 4096;
        int rr[16], cc[16], bb[16], rk[16];
#pragma unroll
        for (int it = 0; it < 16; ++it) {
            int e = eb + it * 256 + tid;
            rk[it] = -1;
            if (e < E) {
                int r = row[e], c = col[e];
                int b = (int)((float)r * binv);
                b = b > 7 ? 7 : b;
                rr[it] = r; cc[it] = c; bb[it] = b;
                rk[it] = atomicAdd(&lcnt[b], 1);
            }
        }
        __syncthreads();
        if (tid < 8) lbase[tid] = atomicAdd(&cursor[tid], lcnt[tid]);
        __syncthreads();
#pragma unroll
        for (int it = 0; it < 16; ++it) {
            if (rk[it] < 0) continue;
            int e = eb + it * 256 + tid;
            int slot = lbase[bb[it]] + rk[it];
            if (slot < C) {
                tup[(size_t)bb[it] * C + slot] =
                    (u64)(unsigned)rr[it] | ((u64)(unsigned)cc[it] << 17) | ((u64)(unsigned)e << 34);
            } else {
                // overflow slow path: recompute from inputs (no U8 dependency).
                const float* za = zs + (size_t)rr[it] * 128;
                const float* zb = zt + (size_t)cc[it] * 128;
                float s = 0.f;
                for (int j = 0; j < 128; ++j) {
                    float h = b1[j];
                    for (int k = 0; k < 128; ++k) h = fmaf(za[k], W1[k * 128 + j], h);
                    for (int k = 0; k < 128; ++k) h = fmaf(zb[k], W1[(128 + k) * 128 + j], h);
                    h = fmaxf(h, 0.f);
                    s = fmaf(h, W2[j], s);
                }
                out[e] = s + b2[0];
            }
        }
    }
}

// ---------------- Pass 2: binned edge decode (UNCHANGED from round 8) ------------
__global__ __launch_bounds__(256) void edge_out(
    const u8* __restrict__ U8, const u8* __restrict__ V8,
    const float* __restrict__ su, const float* __restrict__ sv,
    const u64* __restrict__ tup, const int* __restrict__ cursor,
    const float* __restrict__ W2, const float* __restrict__ b2,
    float* __restrict__ out, int C, int chunks_per_bin)
{
    const int tid = threadIdx.x, m7 = tid & 7, g = tid >> 3;  // 32 groups of 8 lanes
    const int bin = (int)blockIdx.x & 7;
    int chunk = (int)blockIdx.x >> 3;
    int cnt = cursor[bin];
    cnt = cnt < C ? cnt : C;
    if (chunk * 256 >= cnt) return;

    v2h w2e[4], w2o[4];
#pragma unroll
    for (int w = 0; w < 4; ++w) {
        int c0 = 2 * m7 + (w >> 1);
        int tb = (w & 1) * 4;
        w2e[w] = (v2h){(_Float16)W2[(tb + 0) * 16 + c0], (_Float16)W2[(tb + 2) * 16 + c0]};
        w2o[w] = (v2h){(_Float16)W2[(tb + 1) * 16 + c0], (_Float16)W2[(tb + 3) * 16 + c0]};
    }
    const float b2v = b2[0];
    const v2h zero2 = (v2h){(_Float16)0.f, (_Float16)0.f};
    const _Float16 mh = (_Float16)(-1152.f);          // exact in f16
    const v2h m1152 = (v2h){mh, mh};
    const unsigned k64 = 0x64646464u;
    const u64* tb8 = tup + (size_t)bin * C;

    u64 t[8];
#pragma unroll
    for (int it = 0; it < 8; ++it) {
        int idx = chunk * 256 + it * 32 + g;
        t[it] = tb8[idx < cnt ? idx : cnt - 1];
    }

    for (; chunk * 256 < cnt; chunk += chunks_per_bin) {
        const int base = chunk * 256;
        __builtin_amdgcn_sched_barrier(0);

        uint4 qu[8], qv[8];
        float fsu[8], fsv[8];
#pragma unroll
        for (int it = 0; it < 8; ++it) {
            int r = (int)(t[it] & 0x1FFFF);
            int c = (int)((t[it] >> 17) & 0x1FFFF);
            qu[it] = *(const uint4*)(U8 + (size_t)(unsigned)r * 128 + m7 * 16);
            qv[it] = *(const uint4*)(V8 + (size_t)(unsigned)c * 128 + m7 * 16);
            fsu[it] = su[r];
            fsv[it] = sv[c];
        }
        __builtin_amdgcn_sched_barrier(0);

        const int nbase = (chunk + chunks_per_bin) * 256;
        u64 tn[8];
        const bool more = nbase < cnt;
        if (more) {
#pragma unroll
            for (int it = 0; it < 8; ++it) {
                int idx = nbase + it * 32 + g;
                tn[it] = tb8[idx < cnt ? idx : cnt - 1];
            }
        }
        __builtin_amdgcn_sched_barrier(0);

#pragma unroll
        for (int it = 0; it < 8; ++it) {
            const float a = fsu[it], b = fsv[it];
            const _Float16 ah = (_Float16)a, bh = (_Float16)b;
            const v2h a2 = (v2h){ah, ah}, bb2 = (v2h){bh, bh};
            const unsigned int* uw = (const unsigned int*)&qu[it];
            const unsigned int* vw = (const unsigned int*)&qv[it];
            float s = 0.f;
#pragma unroll
            for (int w = 0; w < 4; ++w) {
                v2h due = mk2h(perm_even(uw[w], k64)) + m1152;
                v2h duo = mk2h(perm_odd (uw[w], k64)) + m1152;
                v2h dve = mk2h(perm_even(vw[w], k64)) + m1152;
                v2h dvo = mk2h(perm_odd (vw[w], k64)) + m1152;
                v2h he = __builtin_elementwise_fma(a2, due, bb2 * dve);
                he = __builtin_elementwise_max(he, zero2);
                s = dot2acc(he, w2e[w], s);
                v2h ho = __builtin_elementwise_fma(a2, duo, bb2 * dvo);
                ho = __builtin_elementwise_max(ho, zero2);
                s = dot2acc(ho, w2o[w], s);
            }
            s += __shfl_xor(s, 1);
            s += __shfl_xor(s, 2);
            s += __shfl_xor(s, 4);
            int idx = base + it * 32 + g;
            if (m7 == 0 && idx < cnt) out[(int)(t[it] >> 34)] = s + b2v;
        }
        if (more) {
#pragma unroll
            for (int it = 0; it < 8; ++it) t[it] = tn[it];
        }
    }
}

// ---------------- Fallback (fp32, slow but correct) ------------------------------
__global__ __launch_bounds__(256) void edge_mlp_naive(
    const float* __restrict__ zs, const float* __restrict__ zt,
    const int* __restrict__ row, const int* __restrict__ col,
    const float* __restrict__ W1, const float* __restrict__ b1,
    const float* __restrict__ W2, const float* __restrict__ b2,
    float* __restrict__ out, int E)
{
    __shared__ float zr[4][256];
    int wave = threadIdx.x >> 6, lane = threadIdx.x & 63;
    int e = blockIdx.x * 4 + wave;
    int ec = e < E ? e : E - 1;
    const float* a = zs + (size_t)row[ec] * 128;
    const float* bb = zt + (size_t)col[ec] * 128;
    zr[wave][lane] = a[lane];
    zr[wave][64 + lane] = a[64 + lane];
    zr[wave][128 + lane] = bb[lane];
    zr[wave][192 + lane] = bb[64 + lane];
    __syncthreads();
    float h0 = b1[lane], h1 = b1[64 + lane];
    for (int k = 0; k < 256; ++k) {
        float zk = zr[wave][k];
        h0 = fmaf(zk, W1[k * 128 + lane], h0);
        h1 = fmaf(zk, W1[k * 128 + 64 + lane], h1);
    }
    h0 = h0 > 0.f ? h0 : 0.f;
    h1 = h1 > 0.f ? h1 : 0.f;
    float s = fmaf(h0, W2[lane], h1 * W2[64 + lane]);
    for (int m = 1; m < 64; m <<= 1) s += __shfl_xor(s, m);
    if (lane == 0 && e < E) out[e] = s + b2[0];
}

extern "C" void kernel_launch(void* const* d_in, const int* in_sizes, int n_in,
                              void* d_out, int out_size, void* d_ws, size_t ws_size,
                              hipStream_t stream) {
    const float* zs = (const float*)d_in[0];
    const float* zt = (const float*)d_in[1];
    const int*  row = (const int*)d_in[2];
    const int*  col = (const int*)d_in[3];
    const float* W1 = (const float*)d_in[4];
    const float* b1 = (const float*)d_in[5];
    const float* W2 = (const float*)d_in[6];
    const float* b2 = (const float*)d_in[7];
    float* out = (float*)d_out;

    const int nzs = in_sizes[0];       // 12,800,000 (100K x 128)
    const int nzt = in_sizes[1];       // 6,400,000  (50K x 128)
    const int E   = in_sizes[2];       // 1,000,000
    const int M1  = nzs / 128;
    const int M2  = nzt / 128;

    // per-bin tuple capacity: pow2 >= ~2x expected bin size
    int C = 65536;
    while (C < E / 4 + 1024) C <<= 1;  // 262144 for E=1M

    // ws layout: [tup 8*C u64][cursor 64B][su f32 M1][sv f32 M2][w1p 32K u16][U8][V8]
    const size_t tup_b = (size_t)8 * C * 8;
    const size_t need = tup_b + 64 + (size_t)M1 * 4 + (size_t)M2 * 4 + 65536
                      + (size_t)nzs + (size_t)nzt;
    const bool shapes_ok = (M1 <= 131072) && (M2 <= 131072) && (E > 0) && (E < (1 << 30));

    if (!shapes_ok || ws_size < need) {
        int nb = (E + 3) / 4;
        edge_mlp_naive<<<nb, 256, 0, stream>>>(zs, zt, row, col, W1, b1, W2, b2, out, E);
        return;
    }

    u64* tup    = (u64*)d_ws;
    int* cursor = (int*)((char*)d_ws + tup_b);
    float* su   = (float*)((char*)cursor + 64);
    float* sv   = su + M1;
    u16* w1p    = (u16*)(sv + M2);
    u8* U8      = (u8*)(w1p + 32768);
    u8* V8      = U8 + (size_t)nzs;

    w1_pack<<<16, 256, 0, stream>>>(W1, w1p, cursor);

    const int nU = (M1 + 63) / 64;     // 64-row tiles (round 9)
    const int nV = (M2 + 63) / 64;
    const int nGemm = nU + nV;
    const int nBin = (E + 4095) / 4096;
    const int rpb = (M1 + 7) / 8;
    const float binv = 1.0f / (float)rpb;

    gemm_bin<<<nGemm + nBin, 256, 0, stream>>>(
        zs, zt, w1p, b1, U8, V8, su, sv, M1, M2, nU, nGemm,
        row, col, tup, cursor, E, binv, C, W1, W2, b2, out);

    const int cpb = 512;  // chunks (256 edges) per bin per sweep; grid-strided
    edge_out<<<8 * cpb, 256, 0, stream>>>(U8, V8, su, sv, tup, cursor, W2, b2, out, C, cpb);
}

// Round 10
// 165.136 us; speedup vs baseline: 1.0691x; 1.0691x over previous
//
#include <hip/hip_runtime.h>
#include <hip/hip_bf16.h>
#include <stdint.h>

typedef unsigned short u16;
typedef unsigned char u8;
typedef unsigned long long u64;
typedef __attribute__((ext_vector_type(8))) short short8;
typedef __attribute__((ext_vector_type(4))) float float4v;
typedef __attribute__((ext_vector_type(2))) _Float16 v2h;

// RNE float->bf16
__device__ __forceinline__ u16 f2bf(float x) {
    union { float f; unsigned int u; } v; v.f = x;
    unsigned int r = v.u + 0x7fffu + ((v.u >> 16) & 1u);
    return (u16)(r >> 16);
}

// async global->LDS, 16B per lane (wave-uniform LDS base + lane*16)
__device__ __forceinline__ void ld_g2l16(const void* g, void* l) {
    __builtin_amdgcn_global_load_lds(
        (const __attribute__((address_space(1))) void*)g,
        (__attribute__((address_space(3))) void*)l, 16, 0, 0);
}

// bitcast u32 -> packed f16 pair
__device__ __forceinline__ v2h mk2h(unsigned int u) {
    union { unsigned int u; v2h h; } c; c.u = u; return c.h;
}

// packed fp16 dot-accumulate: s += a.x*b.x + a.y*b.y (fp32 acc)
__device__ __forceinline__ float dot2acc(v2h a, v2h b, float s) {
#if __has_builtin(__builtin_amdgcn_fdot2)
    return __builtin_amdgcn_fdot2(a, b, s, false);
#else
    return fmaf((float)a[0], (float)b[0], fmaf((float)a[1], (float)b[1], s));
#endif
}

// byte-pair -> f16-pair [b, 0x64] via v_perm_b32 (1 op); fallback = and_or path.
__device__ __forceinline__ unsigned perm_even(unsigned x, unsigned k64) {
#if __has_builtin(__builtin_amdgcn_perm)
    return __builtin_amdgcn_perm(x, k64, 0x00060004u);
#else
    return (x & 0x00FF00FFu) | 0x64006400u;
#endif
}
__device__ __forceinline__ unsigned perm_odd(unsigned x, unsigned k64) {
#if __has_builtin(__builtin_amdgcn_perm)
    return __builtin_amdgcn_perm(x, k64, 0x00070005u);
#else
    return ((x >> 8) & 0x00FF00FFu) | 0x64006400u;
#endif
}

// ============================================================================
// int8 U/V storage: PERMUTED per-row layout, PRE-BIASED unsigned:
//   byte p of a row holds (q_col(p) + 128), col(p) = (p&7)*16 + (p>>3)
// ============================================================================

// ---------------- Pass 0: pack W1 into B-frag layout + zero bin cursors ----------
__global__ __launch_bounds__(256) void w1_pack(
    const float* __restrict__ W1, u16* __restrict__ w1p, int* __restrict__ cursor)
{
    if (blockIdx.x == 0 && threadIdx.x < 8) cursor[threadIdx.x] = 0;
    int w = blockIdx.x * 256 + threadIdx.x;   // 0..4095
    int lanep = w & 63, t = (w >> 6) & 7, kc = w >> 9;
    short8 o;
#pragma unroll
    for (int j = 0; j < 8; ++j) {
        int k = kc * 32 + (lanep >> 4) * 8 + j;
        int n = t * 16 + (lanep & 15);
        o[j] = (short)f2bf(W1[k * 128 + n]);
    }
    *(short8*)(w1p + (size_t)w * 8) = o;
}

// ---------------- Pass 1 (merged): dense GEMMs + edge binning --------------------
// ROUND-10: VMEM-issue diagnosis. Rounds 3/5/8/9 all landed 40-49us with MfmaUtil
// ~4%, VALUBusy ~18%, HBM ~20% — idle everywhere. Common factor: 32 B-frag VMEM
// loads/thread (round-9's 64-row tile kept them while halving output -> 17M->29M
// VMEM instrs, 41->45us: time tracks VMEM count at ~1 VMEM/cycle/CU). Fix:
// 128-row tile restored; B-half (32KB) staged to LDS ONCE per block via
// global_load_lds (8 VMEM/thread, no VGPR), inner loop reads B via ds_read_b128
// (LDS pipe, off the VMEM issue path). Per-thread VMEM 57 -> 33.
__global__ __launch_bounds__(256, 3) void gemm_bin(
    const float* __restrict__ zs, const float* __restrict__ zt,
    const u16* __restrict__ w1p, const float* __restrict__ b1,
    u8* __restrict__ U8, u8* __restrict__ V8,
    float* __restrict__ su, float* __restrict__ sv,
    int M1, int M2, int nU, int nGemm,
    const int* __restrict__ row, const int* __restrict__ col,
    u64* __restrict__ tup, int* __restrict__ cursor,
    int E, float binv, int C,
    const float* __restrict__ W1, const float* __restrict__ W2,
    const float* __restrict__ b2, float* __restrict__ out)
{
    __shared__ u16 Blds[16384];   // 32 KB: this block's W1 half in frag layout
    __shared__ int lcnt[8];
    __shared__ int lbase[8];

    if ((int)blockIdx.x < nGemm) {
        // ---------------- GEMM role: 128-row tile, B in LDS, A direct ----------
        const int tid = threadIdx.x, wave = tid >> 6, lane = tid & 63;
        const int m15 = lane & 15, quad = lane >> 4;
        const bool isV = (int)blockIdx.x >= nU;
        const float* zsrc = isV ? zt : zs;
        u8* dst = isV ? V8 : U8;
        float* sdst = isV ? sv : su;
        const int row0 = (isV ? ((int)blockIdx.x - nU) : (int)blockIdx.x) * 128;
        const int M = isV ? M2 : M1;
        const int nrows = (M - row0) < 128 ? (M - row0) : 128;
        const char* wsrc = (const char*)(w1p + (isV ? 16384 : 0));

        // A: 16 dwordx4 direct loads (HBM, deep misses) issued FIRST.
        float4 afl[2][4][2];
#pragma unroll
        for (int mtl = 0; mtl < 2; ++mtl) {
            int r = wave * 32 + mtl * 16 + m15;
            int rr = r < nrows ? r : (nrows - 1);
            const float* rowp = zsrc + (size_t)(row0 + rr) * 128 + quad * 8;
#pragma unroll
            for (int kc = 0; kc < 4; ++kc) {
                afl[mtl][kc][0] = *(const float4*)(rowp + kc * 32);
                afl[mtl][kc][1] = *(const float4*)(rowp + kc * 32 + 4);
            }
        }

        // B: stage 32KB to LDS (8 global_load_lds per thread; linear layout).
#pragma unroll
        for (int it = 0; it < 8; ++it) {
            int off = (wave * 8 + it) * 1024;
            ld_g2l16(wsrc + off + lane * 16, (char*)Blds + off);
        }

        __builtin_amdgcn_s_waitcnt(0);
        __syncthreads();

        short8 Af[2][4];
#pragma unroll
        for (int mtl = 0; mtl < 2; ++mtl)
#pragma unroll
            for (int kc = 0; kc < 4; ++kc) {
                float4 x = afl[mtl][kc][0], y = afl[mtl][kc][1];
                short8 o;
                o[0] = (short)f2bf(x.x); o[1] = (short)f2bf(x.y);
                o[2] = (short)f2bf(x.z); o[3] = (short)f2bf(x.w);
                o[4] = (short)f2bf(y.x); o[5] = (short)f2bf(y.y);
                o[6] = (short)f2bf(y.z); o[7] = (short)f2bf(y.w);
                Af[mtl][kc] = o;
            }

        float4v acc[2][8];
#pragma unroll
        for (int a = 0; a < 2; ++a)
#pragma unroll
            for (int b = 0; b < 8; ++b)
                acc[a][b] = (float4v){0.f, 0.f, 0.f, 0.f};

#pragma unroll
        for (int kc = 0; kc < 4; ++kc) {
#pragma unroll
            for (int t = 0; t < 8; ++t) {
                short8 Bf = *(const short8*)((const char*)Blds + (kc * 8 + t) * 1024 + lane * 16);
#pragma unroll
                for (int mtl = 0; mtl < 2; ++mtl)
                    acc[mtl][t] = __builtin_amdgcn_mfma_f32_16x16x32_bf16(
                        Af[mtl][kc], Bf, acc[mtl][t], 0, 0, 0);
            }
        }

        // epilogue: +b1 (U only), per-row absmax -> int8, pack, dwordx2 store.
        float b1v[8];
#pragma unroll
        for (int t = 0; t < 8; ++t) b1v[t] = isV ? 0.f : b1[t * 16 + m15];

#pragma unroll
        for (int mtl = 0; mtl < 2; ++mtl) {
#pragma unroll
            for (int ri = 0; ri < 4; ++ri) {
                const int rr = wave * 32 + mtl * 16 + quad * 4 + ri;
                float vals[8];
                float vmax = 0.f;
#pragma unroll
                for (int t = 0; t < 8; ++t) {
                    float x = acc[mtl][t][ri] + b1v[t];
                    vals[t] = x;
                    vmax = fmaxf(vmax, fabsf(x));
                }
                vmax = fmaxf(vmax, __shfl_xor(vmax, 1));
                vmax = fmaxf(vmax, __shfl_xor(vmax, 2));
                vmax = fmaxf(vmax, __shfl_xor(vmax, 4));
                vmax = fmaxf(vmax, __shfl_xor(vmax, 8));
                const float scl = vmax * (1.f / 127.f);
                const float rs = vmax > 0.f ? 127.f / vmax : 0.f;
                if (rr < nrows) {
                    if (m15 == 0) sdst[row0 + rr] = scl;
                    unsigned wlo = 0, whi = 0;
#pragma unroll
                    for (int t = 0; t < 4; ++t) {
                        int q = __float2int_rn(vals[t] * rs);
                        q = q > 127 ? 127 : (q < -127 ? -127 : q);
                        wlo |= (unsigned)(q + 128) << (8 * t);   // pre-biased
                    }
#pragma unroll
                    for (int t = 4; t < 8; ++t) {
                        int q = __float2int_rn(vals[t] * rs);
                        q = q > 127 ? 127 : (q < -127 ? -127 : q);
                        whi |= (unsigned)(q + 128) << (8 * (t - 4));
                    }
                    uint2 pk; pk.x = wlo; pk.y = whi;
                    *(uint2*)(dst + (size_t)(row0 + rr) * 128 + m15 * 8) = pk;
                }
            }
        }
    } else {
        // ---------------- BIN role (XCD partitioning by U-row octant) ----------
        const int tid = threadIdx.x;
        if (tid < 8) lcnt[tid] = 0;
        __syncthreads();
        const int eb = ((int)blockIdx.x - nGemm) * 4096;
        int rr[16], cc[16], bb[16], rk[16];
#pragma unroll
        for (int it = 0; it < 16; ++it) {
            int e = eb + it * 256 + tid;
            rk[it] = -1;
            if (e < E) {
                int r = row[e], c = col[e];
                int b = (int)((float)r * binv);
                b = b > 7 ? 7 : b;
                rr[it] = r; cc[it] = c; bb[it] = b;
                rk[it] = atomicAdd(&lcnt[b], 1);
            }
        }
        __syncthreads();
        if (tid < 8) lbase[tid] = atomicAdd(&cursor[tid], lcnt[tid]);
        __syncthreads();
#pragma unroll
        for (int it = 0; it < 16; ++it) {
            if (rk[it] < 0) continue;
            int e = eb + it * 256 + tid;
            int slot = lbase[bb[it]] + rk[it];
            if (slot < C) {
                tup[(size_t)bb[it] * C + slot] =
                    (u64)(unsigned)rr[it] | ((u64)(unsigned)cc[it] << 17) | ((u64)(unsigned)e << 34);
            } else {
                // overflow slow path: recompute from inputs (no U8 dependency).
                const float* za = zs + (size_t)rr[it] * 128;
                const float* zb = zt + (size_t)cc[it] * 128;
                float s = 0.f;
                for (int j = 0; j < 128; ++j) {
                    float h = b1[j];
                    for (int k = 0; k < 128; ++k) h = fmaf(za[k], W1[k * 128 + j], h);
                    for (int k = 0; k < 128; ++k) h = fmaf(zb[k], W1[(128 + k) * 128 + j], h);
                    h = fmaxf(h, 0.f);
                    s = fmaf(h, W2[j], s);
                }
                out[e] = s + b2[0];
            }
        }
    }
}

// ---------------- Pass 2: binned edge decode (UNCHANGED from round 8) ------------
__global__ __launch_bounds__(256) void edge_out(
    const u8* __restrict__ U8, const u8* __restrict__ V8,
    const float* __restrict__ su, const float* __restrict__ sv,
    const u64* __restrict__ tup, const int* __restrict__ cursor,
    const float* __restrict__ W2, const float* __restrict__ b2,
    float* __restrict__ out, int C, int chunks_per_bin)
{
    const int tid = threadIdx.x, m7 = tid & 7, g = tid >> 3;  // 32 groups of 8 lanes
    const int bin = (int)blockIdx.x & 7;
    int chunk = (int)blockIdx.x >> 3;
    int cnt = cursor[bin];
    cnt = cnt < C ? cnt : C;
    if (chunk * 256 >= cnt) return;

    v2h w2e[4], w2o[4];
#pragma unroll
    for (int w = 0; w < 4; ++w) {
        int c0 = 2 * m7 + (w >> 1);
        int tb = (w & 1) * 4;
        w2e[w] = (v2h){(_Float16)W2[(tb + 0) * 16 + c0], (_Float16)W2[(tb + 2) * 16 + c0]};
        w2o[w] = (v2h){(_Float16)W2[(tb + 1) * 16 + c0], (_Float16)W2[(tb + 3) * 16 + c0]};
    }
    const float b2v = b2[0];
    const v2h zero2 = (v2h){(_Float16)0.f, (_Float16)0.f};
    const _Float16 mh = (_Float16)(-1152.f);          // exact in f16
    const v2h m1152 = (v2h){mh, mh};
    const unsigned k64 = 0x64646464u;
    const u64* tb8 = tup + (size_t)bin * C;

    u64 t[8];
#pragma unroll
    for (int it = 0; it < 8; ++it) {
        int idx = chunk * 256 + it * 32 + g;
        t[it] = tb8[idx < cnt ? idx : cnt - 1];
    }

    for (; chunk * 256 < cnt; chunk += chunks_per_bin) {
        const int base = chunk * 256;
        __builtin_amdgcn_sched_barrier(0);

        uint4 qu[8], qv[8];
        float fsu[8], fsv[8];
#pragma unroll
        for (int it = 0; it < 8; ++it) {
            int r = (int)(t[it] & 0x1FFFF);
            int c = (int)((t[it] >> 17) & 0x1FFFF);
            qu[it] = *(const uint4*)(U8 + (size_t)(unsigned)r * 128 + m7 * 16);
            qv[it] = *(const uint4*)(V8 + (size_t)(unsigned)c * 128 + m7 * 16);
            fsu[it] = su[r];
            fsv[it] = sv[c];
        }
        __builtin_amdgcn_sched_barrier(0);

        const int nbase = (chunk + chunks_per_bin) * 256;
        u64 tn[8];
        const bool more = nbase < cnt;
        if (more) {
#pragma unroll
            for (int it = 0; it < 8; ++it) {
                int idx = nbase + it * 32 + g;
                tn[it] = tb8[idx < cnt ? idx : cnt - 1];
            }
        }
        __builtin_amdgcn_sched_barrier(0);

#pragma unroll
        for (int it = 0; it < 8; ++it) {
            const float a = fsu[it], b = fsv[it];
            const _Float16 ah = (_Float16)a, bh = (_Float16)b;
            const v2h a2 = (v2h){ah, ah}, bb2 = (v2h){bh, bh};
            const unsigned int* uw = (const unsigned int*)&qu[it];
            const unsigned int* vw = (const unsigned int*)&qv[it];
            float s = 0.f;
#pragma unroll
            for (int w = 0; w < 4; ++w) {
                v2h due = mk2h(perm_even(uw[w], k64)) + m1152;
                v2h duo = mk2h(perm_odd (uw[w], k64)) + m1152;
                v2h dve = mk2h(perm_even(vw[w], k64)) + m1152;
                v2h dvo = mk2h(perm_odd (vw[w], k64)) + m1152;
                v2h he = __builtin_elementwise_fma(a2, due, bb2 * dve);
                he = __builtin_elementwise_max(he, zero2);
                s = dot2acc(he, w2e[w], s);
                v2h ho = __builtin_elementwise_fma(a2, duo, bb2 * dvo);
                ho = __builtin_elementwise_max(ho, zero2);
                s = dot2acc(ho, w2o[w], s);
            }
            s += __shfl_xor(s, 1);
            s += __shfl_xor(s, 2);
            s += __shfl_xor(s, 4);
            int idx = base + it * 32 + g;
            if (m7 == 0 && idx < cnt) out[(int)(t[it] >> 34)] = s + b2v;
        }
        if (more) {
#pragma unroll
            for (int it = 0; it < 8; ++it) t[it] = tn[it];
        }
    }
}

// ---------------- Fallback (fp32, slow but correct) ------------------------------
__global__ __launch_bounds__(256) void edge_mlp_naive(
    const float* __restrict__ zs, const float* __restrict__ zt,
    const int* __restrict__ row, const int* __restrict__ col,
    const float* __restrict__ W1, const float* __restrict__ b1,
    const float* __restrict__ W2, const float* __restrict__ b2,
    float* __restrict__ out, int E)
{
    __shared__ float zr[4][256];
    int wave = threadIdx.x >> 6, lane = threadIdx.x & 63;
    int e = blockIdx.x * 4 + wave;
    int ec = e < E ? e : E - 1;
    const float* a = zs + (size_t)row[ec] * 128;
    const float* bb = zt + (size_t)col[ec] * 128;
    zr[wave][lane] = a[lane];
    zr[wave][64 + lane] = a[64 + lane];
    zr[wave][128 + lane] = bb[lane];
    zr[wave][192 + lane] = bb[64 + lane];
    __syncthreads();
    float h0 = b1[lane], h1 = b1[64 + lane];
    for (int k = 0; k < 256; ++k) {
        float zk = zr[wave][k];
        h0 = fmaf(zk, W1[k * 128 + lane], h0);
        h1 = fmaf(zk, W1[k * 128 + 64 + lane], h1);
    }
    h0 = h0 > 0.f ? h0 : 0.f;
    h1 = h1 > 0.f ? h1 : 0.f;
    float s = fmaf(h0, W2[lane], h1 * W2[64 + lane]);
    for (int m = 1; m < 64; m <<= 1) s += __shfl_xor(s, m);
    if (lane == 0 && e < E) out[e] = s + b2[0];
}

extern "C" void kernel_launch(void* const* d_in, const int* in_sizes, int n_in,
                              void* d_out, int out_size, void* d_ws, size_t ws_size,
                              hipStream_t stream) {
    const float* zs = (const float*)d_in[0];
    const float* zt = (const float*)d_in[1];
    const int*  row = (const int*)d_in[2];
    const int*  col = (const int*)d_in[3];
    const float* W1 = (const float*)d_in[4];
    const float* b1 = (const float*)d_in[5];
    const float* W2 = (const float*)d_in[6];
    const float* b2 = (const float*)d_in[7];
    float* out = (float*)d_out;

    const int nzs = in_sizes[0];       // 12,800,000 (100K x 128)
    const int nzt = in_sizes[1];       // 6,400,000  (50K x 128)
    const int E   = in_sizes[2];       // 1,000,000
    const int M1  = nzs / 128;
    const int M2  = nzt / 128;

    // per-bin tuple capacity: pow2 >= ~2x expected bin size
    int C = 65536;
    while (C < E / 4 + 1024) C <<= 1;  // 262144 for E=1M

    // ws layout: [tup 8*C u64][cursor 64B][su f32 M1][sv f32 M2][w1p 32K u16][U8][V8]
    const size_t tup_b = (size_t)8 * C * 8;
    const size_t need = tup_b + 64 + (size_t)M1 * 4 + (size_t)M2 * 4 + 65536
                      + (size_t)nzs + (size_t)nzt;
    const bool shapes_ok = (M1 <= 131072) && (M2 <= 131072) && (E > 0) && (E < (1 << 30));

    if (!shapes_ok || ws_size < need) {
        int nb = (E + 3) / 4;
        edge_mlp_naive<<<nb, 256, 0, stream>>>(zs, zt, row, col, W1, b1, W2, b2, out, E);
        return;
    }

    u64* tup    = (u64*)d_ws;
    int* cursor = (int*)((char*)d_ws + tup_b);
    float* su   = (float*)((char*)cursor + 64);
    float* sv   = su + M1;
    u16* w1p    = (u16*)(sv + M2);
    u8* U8      = (u8*)(w1p + 32768);
    u8* V8      = U8 + (size_t)nzs;

    w1_pack<<<16, 256, 0, stream>>>(W1, w1p, cursor);

    const int nU = (M1 + 127) / 128;   // 128-row tiles restored (round 10)
    const int nV = (M2 + 127) / 128;
    const int nGemm = nU + nV;
    const int nBin = (E + 4095) / 4096;
    const int rpb = (M1 + 7) / 8;
    const float binv = 1.0f / (float)rpb;

    gemm_bin<<<nGemm + nBin, 256, 0, stream>>>(
        zs, zt, w1p, b1, U8, V8, su, sv, M1, M2, nU, nGemm,
        row, col, tup, cursor, E, binv, C, W1, W2, b2, out);

    const int cpb = 512;  // chunks (256 edges) per bin per sweep; grid-strided
    edge_out<<<8 * cpb, 256, 0, stream>>>(U8, V8, su, sv, tup, cursor, W2, b2, out, C, cpb);
}